// Round 3
// baseline (171.562 us; speedup 1.0000x reference)
//
#include <hip/hip_runtime.h>

typedef __attribute__((ext_vector_type(8))) short s16x8;
typedef __attribute__((ext_vector_type(4))) float f32x4;
typedef __attribute__((ext_vector_type(4))) unsigned u32x4;

#define WAVES 8
#define TROWS 32
#define RPB (WAVES * TROWS)   // 256 rows per block-tile

__device__ __forceinline__ short f2bf(float f) {
    unsigned u = __float_as_uint(f);
    u += 0x7fffu + ((u >> 16) & 1u);
    return (short)(u >> 16);
}

__device__ __forceinline__ unsigned cvt_pk(float lo, float hi) {
    unsigned r;
    asm("v_cvt_pk_bf16_f32 %0, %1, %2" : "=v"(r) : "v"(lo), "v"(hi));
    return r;
}

// swizzled ushort index into a [rows][128] bf16 tile (col multiple of 8 for 16B ops)
__device__ __forceinline__ int swz(int row, int col) {
    return (row * 128 + col) ^ ((row & 7) << 3);
}

// row_ror:S within 16-lane rows (DPP ctrl 0x120|S needs a parse-time constant)
template <int S>
__device__ __forceinline__ float dpp_ror(float v) {
    int x = __builtin_amdgcn_update_dpp(0, __float_as_int(v), 0x120 | S, 0xf, 0xf, false);
    return __int_as_float(x);
}

// sum across each aligned 16-lane group, VALU-only
__device__ __forceinline__ float red16(float v) {
    v += dpp_ror<1>(v);
    v += dpp_ror<2>(v);
    v += dpp_ror<4>(v);
    v += dpp_ror<8>(v);
    return v;
}

// write 8 floats as bf16x8 to swizzled tile
__device__ __forceinline__ void store8(short* tile, int row, int col, float4 a, float4 b) {
    u32x4 v;
    v[0] = cvt_pk(a.x, a.y); v[1] = cvt_pk(a.z, a.w);
    v[2] = cvt_pk(b.x, b.y); v[3] = cvt_pk(b.z, b.w);
    *(u32x4*)(tile + swz(row, col)) = v;
}

// per-lane gather base pointer for (tile tI, row j within wave, half q)
__device__ __forceinline__ const float4* gaddr(const float* topo, int kg, int nRows,
                                               int wj_abs, int q, int i0, int i1, int i2) {
    int Rc = min(max(wj_abs, 0), nRows - 1);
    int n = Rc / 3, f = Rc - 3 * n;
    int a0 = i0, a1 = i1, a2 = i2;
    if (q) {
        if (f == 0) a0 = max(i0 - 1, 0);
        else if (f == 1) a1 = max(i1 - 1, 0);
        else a2 = max(i2 - 1, 0);
    }
    return (const float4*)(topo + (((long)a0 * kg + a1) * kg + a2) * 64);
}

__launch_bounds__(512, 2)
__global__ void edgeface_kernel(
    const float* __restrict__ topo, const int* __restrict__ esid,
    const float* __restrict__ W1, const float* __restrict__ b1,
    const float* __restrict__ W2, const float* __restrict__ b2,
    const float* __restrict__ W3, const float* __restrict__ b3,
    float* __restrict__ out, int nRows, int kg)
{
    __shared__ __align__(16) short sW1[128 * 128];   // Wt[n][k], swizzled bf16
    __shared__ __align__(16) short sW2[128 * 128];
    __shared__ __align__(16) short sX[WAVES * TROWS * 128]; // per-wave X/H tile (64KB)

    const int tid = threadIdx.x;

    for (int idx = tid; idx < 128 * 128; idx += 512) {
        int kk = idx >> 7, n = idx & 127;
        int d = swz(n, kk);
        sW1[d] = f2bf(W1[idx]);
        sW2[d] = f2bf(W2[idx]);
    }
    __syncthreads();

    const int w = tid >> 6, lane = tid & 63;
    short* tile = sX + w * (TROWS * 128);
    const int r = lane & 15;   // A-row / D-col within 16
    const int g = lane >> 4;   // k-quarter / D-row-group

    // hoisted per-lane constants (biases, W3 logit-diff)
    float rb1[8], rb2[8], w3d[8];
    #pragma unroll
    for (int t = 0; t < 8; ++t) {
        int c = t * 16 + r;
        rb1[t] = b1[c];
        rb2[t] = b2[c];
        w3d[t] = W3[c * 2 + 1] - W3[c * 2 + 0];
    }
    const float b3d = b3[1] - b3[0];

    const int j = lane >> 1, q = lane & 1;   // gather: 2 lanes per row
    const int G = gridDim.x;
    const int nTiles = (nRows + RPB - 1) / RPB;
    const int wjOff = w * TROWS + j;

    // ---------------- prologue: stage X for first tile, preload esid for next ----------------
    int tI0 = blockIdx.x;
    int eA0, eA1, eA2;
    {
        int Rc = min(max(tI0 * RPB + wjOff, 0), nRows - 1);
        int n = Rc / 3;
        eA0 = esid[n * 3 + 0]; eA1 = esid[n * 3 + 1]; eA2 = esid[n * 3 + 2];
    }
    {
        const float4* p = gaddr(topo, kg, nRows, tI0 * RPB + wjOff, q, eA0, eA1, eA2);
        float4 st[16];
        #pragma unroll
        for (int m = 0; m < 16; ++m) st[m] = p[m];
        // preload esid for tile tI0+G while loads are in flight
        int Rc = min(max((tI0 + G) * RPB + wjOff, 0), nRows - 1);
        int n = Rc / 3;
        eA0 = esid[n * 3 + 0]; eA1 = esid[n * 3 + 1]; eA2 = esid[n * 3 + 2];
        #pragma unroll
        for (int m = 0; m < 8; ++m)
            store8(tile, j, q * 64 + m * 8, st[2 * m], st[2 * m + 1]);
    }

    // ---------------- main pipelined loop ----------------
    for (int tI = tI0; tI < nTiles; tI += G) {
        // 1. layer-1 A fragments (consumes X_t)
        s16x8 a0[4], a1[4];
        #pragma unroll
        for (int ks = 0; ks < 4; ++ks) {
            a0[ks] = *(const s16x8*)(tile + swz(r,      ks * 32 + g * 8));
            a1[ks] = *(const s16x8*)(tile + swz(16 + r, ks * 32 + g * 8));
        }

        // 2. issue next tile's topo gather (esid already in eA*)
        float4 st[16];
        {
            const float4* p = gaddr(topo, kg, nRows, (tI + G) * RPB + wjOff, q, eA0, eA1, eA2);
            #pragma unroll
            for (int m = 0; m < 16; ++m) st[m] = p[m];
        }

        // 3. layer-1 MFMA (B-fragment read amortized over 2 row-subtiles)
        f32x4 acc[2][8];
        #pragma unroll
        for (int t = 0; t < 8; ++t) {
            f32x4 c0 = {0.f, 0.f, 0.f, 0.f}, c1 = {0.f, 0.f, 0.f, 0.f};
            #pragma unroll
            for (int ks = 0; ks < 4; ++ks) {
                s16x8 bf = *(const s16x8*)(sW1 + swz(t * 16 + r, ks * 32 + g * 8));
                c0 = __builtin_amdgcn_mfma_f32_16x16x32_bf16(a0[ks], bf, c0, 0, 0, 0);
                c1 = __builtin_amdgcn_mfma_f32_16x16x32_bf16(a1[ks], bf, c1, 0, 0, 0);
            }
            acc[0][t] = c0; acc[1][t] = c1;
        }

        // 4. preload esid for tile tI+2G
        {
            int Rc = min(max((tI + 2 * G) * RPB + wjOff, 0), nRows - 1);
            int n = Rc / 3;
            eA0 = esid[n * 3 + 0]; eA1 = esid[n * 3 + 1]; eA2 = esid[n * 3 + 2];
        }

        // 5. layer-1 epilogue: H1 -> tile (in place; X_t fully consumed at step 1)
        #pragma unroll
        for (int sub = 0; sub < 2; ++sub) {
            #pragma unroll
            for (int t = 0; t < 8; ++t) {
                float x0 = fmaxf(acc[sub][t][0] + rb1[t], 0.f);
                float x1 = fmaxf(acc[sub][t][1] + rb1[t], 0.f);
                float x2 = fmaxf(acc[sub][t][2] + rb1[t], 0.f);
                float x3 = fmaxf(acc[sub][t][3] + rb1[t], 0.f);
                unsigned pA = cvt_pk(x0, x1), pB = cvt_pk(x2, x3);
                int row0 = sub * 16 + g * 4, col = t * 16 + r;
                tile[swz(row0 + 0, col)] = (short)pA;
                tile[swz(row0 + 1, col)] = (short)(pA >> 16);
                tile[swz(row0 + 2, col)] = (short)pB;
                tile[swz(row0 + 3, col)] = (short)(pB >> 16);
            }
        }

        // 6. layer-2 A fragments (consumes H1; tile dead afterwards)
        #pragma unroll
        for (int ks = 0; ks < 4; ++ks) {
            a0[ks] = *(const s16x8*)(tile + swz(r,      ks * 32 + g * 8));
            a1[ks] = *(const s16x8*)(tile + swz(16 + r, ks * 32 + g * 8));
        }

        // 7. write staged gather -> tile = X_{t+G} (DS is in-order per wave: reads in 6 land first)
        #pragma unroll
        for (int m = 0; m < 8; ++m)
            store8(tile, j, q * 64 + m * 8, st[2 * m], st[2 * m + 1]);

        // 8. layer-2 MFMA
        f32x4 acc2[2][8];
        #pragma unroll
        for (int t = 0; t < 8; ++t) {
            f32x4 c0 = {0.f, 0.f, 0.f, 0.f}, c1 = {0.f, 0.f, 0.f, 0.f};
            #pragma unroll
            for (int ks = 0; ks < 4; ++ks) {
                s16x8 bf = *(const s16x8*)(sW2 + swz(t * 16 + r, ks * 32 + g * 8));
                c0 = __builtin_amdgcn_mfma_f32_16x16x32_bf16(a0[ks], bf, c0, 0, 0, 0);
                c1 = __builtin_amdgcn_mfma_f32_16x16x32_bf16(a1[ks], bf, c1, 0, 0, 0);
            }
            acc2[0][t] = c0; acc2[1][t] = c1;
        }

        // 9. fused layer-2 bias/relu + layer-3 logit-diff dot (all in registers)
        float pd[2][4] = {{0.f,0.f,0.f,0.f},{0.f,0.f,0.f,0.f}};
        #pragma unroll
        for (int sub = 0; sub < 2; ++sub) {
            #pragma unroll
            for (int t = 0; t < 8; ++t) {
                #pragma unroll
                for (int i = 0; i < 4; ++i) {
                    float h = fmaxf(acc2[sub][t][i] + rb2[t], 0.f);
                    pd[sub][i] = fmaf(h, w3d[t], pd[sub][i]);
                }
            }
        }
        #pragma unroll
        for (int sub = 0; sub < 2; ++sub)
            #pragma unroll
            for (int i = 0; i < 4; ++i)
                pd[sub][i] = red16(pd[sub][i]);   // sum over the 16 r-lanes (cols)

        // 10. softmax + store: lane r = i*2 + o (r<8) handles (row-within-quad i, output o)
        if (r < 8) {
            int i = r >> 1, o = r & 1;
            #pragma unroll
            for (int sub = 0; sub < 2; ++sub) {
                float dsum = (i == 0) ? pd[sub][0] : (i == 1) ? pd[sub][1]
                           : (i == 2) ? pd[sub][2] : pd[sub][3];
                float d = dsum + b3d;
                float p = 1.f / (1.f + __expf(o ? -d : d));
                int R = tI * RPB + w * TROWS + sub * 16 + g * 4 + i;
                if (R < nRows) {
                    int n = R / 3, f = R - 3 * n;
                    out[n * 6 + o * 3 + f] = p;   // (N, 2, 3)
                }
            }
        }
    }
}

extern "C" void kernel_launch(void* const* d_in, const int* in_sizes, int n_in,
                              void* d_out, int out_size, void* d_ws, size_t ws_size,
                              hipStream_t stream) {
    const float* topo = (const float*)d_in[0];
    const int*   esid = (const int*)d_in[1];
    const float* W1 = (const float*)d_in[2];
    const float* b1 = (const float*)d_in[3];
    const float* W2 = (const float*)d_in[4];
    const float* b2 = (const float*)d_in[5];
    const float* W3 = (const float*)d_in[6];
    const float* b3 = (const float*)d_in[7];
    float* out = (float*)d_out;

    int nRows = in_sizes[1];
    int H = in_sizes[3];
    int F = (in_sizes[2] / H) / 2;
    long vol = (long)in_sizes[0] / F;
    int kg = 1;
    while ((long)(kg + 1) * (kg + 1) * (kg + 1) <= vol) ++kg;

    if (nRows <= 0) return;
    edgeface_kernel<<<dim3(256), dim3(512), 0, stream>>>(
        topo, esid, W1, b1, W2, b2, W3, b3, out, nRows, kg);
}

// Round 4
// 84.552 us; speedup vs baseline: 2.0291x; 2.0291x over previous
//
#include <hip/hip_runtime.h>

typedef __attribute__((ext_vector_type(8))) short s16x8;
typedef __attribute__((ext_vector_type(4))) float f32x4;
typedef __attribute__((ext_vector_type(4))) unsigned u32x4;

#define THREADS 768
#define WAVES 12
#define TROWS 16
#define RPB (WAVES * TROWS)   // 192 rows per block-tile

__device__ __forceinline__ short f2bf(float f) {
    unsigned u = __float_as_uint(f);
    u += 0x7fffu + ((u >> 16) & 1u);
    return (short)(u >> 16);
}

__device__ __forceinline__ unsigned cvt_pk(float lo, float hi) {
    unsigned r;
    asm("v_cvt_pk_bf16_f32 %0, %1, %2" : "=v"(r) : "v"(lo), "v"(hi));
    return r;
}

// swizzled ushort index into a [rows][128] bf16 tile (col multiple of 8 for 16B ops)
__device__ __forceinline__ int swz(int row, int col) {
    return (row * 128 + col) ^ ((row & 7) << 3);
}

// row_ror:S within 16-lane rows (DPP ctrl needs parse-time constant)
template <int S>
__device__ __forceinline__ float dpp_ror(float v) {
    int x = __builtin_amdgcn_update_dpp(0, __float_as_int(v), 0x120 | S, 0xf, 0xf, false);
    return __int_as_float(x);
}

__device__ __forceinline__ float red16(float v) {
    v += dpp_ror<1>(v);
    v += dpp_ror<2>(v);
    v += dpp_ror<4>(v);
    v += dpp_ror<8>(v);
    return v;
}

__device__ __forceinline__ void store8(short* tile, int row, int col, float4 a, float4 b) {
    u32x4 v;
    v[0] = cvt_pk(a.x, a.y); v[1] = cvt_pk(a.z, a.w);
    v[2] = cvt_pk(b.x, b.y); v[3] = cvt_pk(b.z, b.w);
    *(u32x4*)(tile + swz(row, col)) = v;
}

__launch_bounds__(THREADS, 3)
__global__ void edgeface_kernel(
    const float* __restrict__ topo, const int* __restrict__ esid,
    const float* __restrict__ W1, const float* __restrict__ b1,
    const float* __restrict__ W2, const float* __restrict__ b2,
    const float* __restrict__ W3, const float* __restrict__ b3,
    float* __restrict__ out, int nRows, int kg)
{
    __shared__ __align__(16) short sW1[128 * 128];   // Wt[n][k], swizzled bf16 (32KB)
    __shared__ __align__(16) short sW2[128 * 128];   // 32KB
    __shared__ __align__(16) short sX[WAVES * TROWS * 128]; // per-wave tiles (48KB)

    const int tid = threadIdx.x;

    for (int idx = tid; idx < 128 * 128; idx += THREADS) {
        int kk = idx >> 7, n = idx & 127;
        int d = swz(n, kk);
        sW1[d] = f2bf(W1[idx]);
        sW2[d] = f2bf(W2[idx]);
    }
    __syncthreads();

    const int w = tid >> 6, lane = tid & 63;
    short* tile = sX + w * (TROWS * 128);
    const int r = lane & 15;   // A-row / D-col within 16
    const int g = lane >> 4;   // k-quarter / D-row-group

    // hoisted per-lane constants
    float rb1[8], rb2[8], w3d[8];
    #pragma unroll
    for (int t = 0; t < 8; ++t) {
        int c = t * 16 + r;
        rb1[t] = b1[c];
        rb2[t] = b2[c];
        w3d[t] = W3[c * 2 + 1] - W3[c * 2 + 0];
    }
    const float b3d = b3[1] - b3[0];

    const int j = lane >> 2, q = lane & 3;   // gather: 4 lanes per row
    const int G = gridDim.x;
    const int nTiles = (nRows + RPB - 1) / RPB;
    const int wj = w * TROWS + j;

    // esid for first tile
    int e0, e1, e2;
    {
        int Rc = min(blockIdx.x * RPB + wj, nRows - 1);
        int n = Rc / 3;
        e0 = esid[n * 3 + 0]; e1 = esid[n * 3 + 1]; e2 = esid[n * 3 + 2];
    }

    for (int tI = blockIdx.x; tI < nTiles; tI += G) {
        // ---- gather current tile (esid already resident in e0..e2) ----
        int Rc = min(tI * RPB + wj, nRows - 1);
        int f = Rc - 3 * (Rc / 3);
        long be = (((long)e0 * kg + e1) * kg + e2) * 64;
        int a0 = (f == 0) ? max(e0 - 1, 0) : e0;
        int a1 = (f == 1) ? max(e1 - 1, 0) : e1;
        int a2 = (f == 2) ? max(e2 - 1, 0) : e2;
        long bn = (((long)a0 * kg + a1) * kg + a2) * 64;
        const float4* pe = (const float4*)(topo + be) + q * 4;
        const float4* pn = (const float4*)(topo + bn) + q * 4;
        float4 s0 = pe[0], s1 = pe[1], s2 = pe[2], s3 = pe[3];
        float4 s4 = pn[0], s5 = pn[1], s6 = pn[2], s7 = pn[3];

        // preload esid for the next tile while gather is in flight
        {
            int nR = min((tI + G) * RPB + wj, nRows - 1);
            int nn = nR / 3;
            e0 = esid[nn * 3 + 0]; e1 = esid[nn * 3 + 1]; e2 = esid[nn * 3 + 2];
        }

        // stage X (compiler inserts vmcnt waits here)
        store8(tile, j, q * 16 + 0, s0, s1);
        store8(tile, j, q * 16 + 8, s2, s3);
        store8(tile, j, 64 + q * 16 + 0, s4, s5);
        store8(tile, j, 64 + q * 16 + 8, s6, s7);

        // ---- layer 1: H1 = relu(X @ W1 + b1) ----
        s16x8 a[4];
        #pragma unroll
        for (int ks = 0; ks < 4; ++ks)
            a[ks] = *(const s16x8*)(tile + swz(r, ks * 32 + g * 8));
        f32x4 acc[8];
        #pragma unroll
        for (int t = 0; t < 8; ++t) {
            f32x4 c = {0.f, 0.f, 0.f, 0.f};
            #pragma unroll
            for (int ks = 0; ks < 4; ++ks) {
                s16x8 bf = *(const s16x8*)(sW1 + swz(t * 16 + r, ks * 32 + g * 8));
                c = __builtin_amdgcn_mfma_f32_16x16x32_bf16(a[ks], bf, c, 0, 0, 0);
            }
            acc[t] = c;
        }
        #pragma unroll
        for (int t = 0; t < 8; ++t) {
            float x0 = fmaxf(acc[t][0] + rb1[t], 0.f);
            float x1 = fmaxf(acc[t][1] + rb1[t], 0.f);
            float x2 = fmaxf(acc[t][2] + rb1[t], 0.f);
            float x3 = fmaxf(acc[t][3] + rb1[t], 0.f);
            unsigned pA = cvt_pk(x0, x1), pB = cvt_pk(x2, x3);
            int row0 = g * 4, col = t * 16 + r;
            tile[swz(row0 + 0, col)] = (short)pA;
            tile[swz(row0 + 1, col)] = (short)(pA >> 16);
            tile[swz(row0 + 2, col)] = (short)pB;
            tile[swz(row0 + 3, col)] = (short)(pB >> 16);
        }

        // ---- layer 2 MFMA + fused layer-3 logit-diff (in registers) ----
        #pragma unroll
        for (int ks = 0; ks < 4; ++ks)
            a[ks] = *(const s16x8*)(tile + swz(r, ks * 32 + g * 8));
        #pragma unroll
        for (int t = 0; t < 8; ++t) {
            f32x4 c = {0.f, 0.f, 0.f, 0.f};
            #pragma unroll
            for (int ks = 0; ks < 4; ++ks) {
                s16x8 bf = *(const s16x8*)(sW2 + swz(t * 16 + r, ks * 32 + g * 8));
                c = __builtin_amdgcn_mfma_f32_16x16x32_bf16(a[ks], bf, c, 0, 0, 0);
            }
            acc[t] = c;
        }
        float pd[4] = {0.f, 0.f, 0.f, 0.f};
        #pragma unroll
        for (int t = 0; t < 8; ++t) {
            #pragma unroll
            for (int i = 0; i < 4; ++i) {
                float h = fmaxf(acc[t][i] + rb2[t], 0.f);
                pd[i] = fmaf(h, w3d[t], pd[i]);
            }
        }
        #pragma unroll
        for (int i = 0; i < 4; ++i)
            pd[i] = red16(pd[i]);   // sum over the 16 r-lanes (H2 columns)

        // ---- softmax + store: lane r = i*2 + o (r<8) ----
        if (r < 8) {
            int i = r >> 1, o = r & 1;
            float dsum = (i == 0) ? pd[0] : (i == 1) ? pd[1] : (i == 2) ? pd[2] : pd[3];
            float d = dsum + b3d;
            float p = 1.f / (1.f + __expf(o ? -d : d));
            int R = tI * RPB + w * TROWS + g * 4 + i;
            if (R < nRows) {
                int n = R / 3, ff = R - 3 * n;
                out[n * 6 + o * 3 + ff] = p;   // (N, 2, 3)
            }
        }
    }
}

extern "C" void kernel_launch(void* const* d_in, const int* in_sizes, int n_in,
                              void* d_out, int out_size, void* d_ws, size_t ws_size,
                              hipStream_t stream) {
    const float* topo = (const float*)d_in[0];
    const int*   esid = (const int*)d_in[1];
    const float* W1 = (const float*)d_in[2];
    const float* b1 = (const float*)d_in[3];
    const float* W2 = (const float*)d_in[4];
    const float* b2 = (const float*)d_in[5];
    const float* W3 = (const float*)d_in[6];
    const float* b3 = (const float*)d_in[7];
    float* out = (float*)d_out;

    int nRows = in_sizes[1];
    int H = in_sizes[3];
    int F = (in_sizes[2] / H) / 2;
    long vol = (long)in_sizes[0] / F;
    int kg = 1;
    while ((long)(kg + 1) * (kg + 1) * (kg + 1) <= vol) ++kg;

    if (nRows <= 0) return;
    edgeface_kernel<<<dim3(256), dim3(THREADS), 0, stream>>>(
        topo, esid, W1, b1, W2, b2, W3, b3, out, nRows, kg);
}